// Round 5
// baseline (653.477 us; speedup 1.0000x reference)
//
#include <hip/hip_runtime.h>
#include <hip/hip_bf16.h>

#define RES 128
#define R3  (RES * RES * RES)   // 2097152

// Problem-fixed shapes (from reference setup_inputs)
constexpr int Bn = 4, Cn = 16, Hn = 256, Wn = 256, FHn = 32, FWn = 32;
constexpr int HW = Hn * Wn;     // 65536
constexpr int NPIX = Bn * HW;   // 262144

// sigmoid(x) > 0.75  <=>  x > ln(3); exact for fp32-grid inputs in fp64
// (disagreement needs |x - ln3| < ~1e-15; fp32 spacing there is ~6e-8).
#define LN3 1.0986122886681098

// Native clang vector type — __builtin_nontemporal_store requires it
// (HIP_vector_type float4 is a struct and is rejected).
typedef float vfloat4 __attribute__((ext_vector_type(4)));

// ---------------------------------------------------------------------------
// Init per-batch lower mins (fp64) to BIG. Tiny; must precede the atomicMins.
// (Do NOT rely on 0xAA poison bit patterns for min-identity.)
// ---------------------------------------------------------------------------
__global__ void init_lower_k(double* __restrict__ lower) {
    int i = threadIdx.x;
    if (i < Bn * 3) lower[i] = 1e10;
}

// Validity: mask_logit > ln3 AND all 3 nocs channels strictly positive.
__device__ __forceinline__ bool pixel_valid(const float* __restrict__ nocs,
                                            const float* __restrict__ mlog,
                                            int p, double& n0, double& n1, double& n2) {
    if (!((double)mlog[p] > LN3)) return false;
    int b  = p >> 16;        // p / HW
    int hw = p & (HW - 1);
    const float* nb = nocs + (size_t)b * 3 * HW + hw;
    n0 = (double)nb[0];
    n1 = (double)nb[HW];
    n2 = (double)nb[2 * HW];
    return (n0 > 0.0) & (n1 > 0.0) & (n2 > 0.0);
}

__device__ __forceinline__ double wave_min(double v) {
    #pragma unroll
    for (int off = 32; off > 0; off >>= 1)
        v = fmin(v, __shfl_down(v, off, 64));
    return v;
}

// ---------------------------------------------------------------------------
// Fused pass: (a) per-batch fp64 min of pc = (nocs+t)*s over valid pixels
// (4 MiB of reads — hides under the write stream), then (b) grid-stride
// zero of the 512 MiB output grid with nontemporal 16B stores.
// 1024 blocks x 256 threads: one pixel per thread for the reduce; 128
// vfloat4 stores per thread for the zero.
// All valid pc >= 0 so unsigned-bit atomicMin preserves float ordering.
// ---------------------------------------------------------------------------
__global__ __launch_bounds__(256) void fused_reduce_zero_k(
        const float* __restrict__ nocs, const float* __restrict__ mlog,
        const float* __restrict__ trans, const float* __restrict__ scale,
        unsigned long long* __restrict__ lower_bits,
        vfloat4* __restrict__ out4, int n4) {
    __shared__ double s0[4], s1[4], s2[4];
    int tid = threadIdx.x;
    int p   = blockIdx.x * 256 + tid;
    int b   = p >> 16;                 // whole block shares b (HW % 256 == 0)

    // --- (a) reduce ---
    double m0 = 1e10, m1 = 1e10, m2 = 1e10;
    double n0, n1, n2;
    if (pixel_valid(nocs, mlog, p, n0, n1, n2)) {
        double sc = (double)scale[b];
        m0 = (n0 + (double)trans[b * 3 + 0]) * sc;
        m1 = (n1 + (double)trans[b * 3 + 1]) * sc;
        m2 = (n2 + (double)trans[b * 3 + 2]) * sc;
    }
    m0 = wave_min(m0); m1 = wave_min(m1); m2 = wave_min(m2);
    int wave = tid >> 6;
    if ((tid & 63) == 0) { s0[wave] = m0; s1[wave] = m1; s2[wave] = m2; }
    __syncthreads();
    if (tid == 0) {
        m0 = fmin(fmin(s0[0], s0[1]), fmin(s0[2], s0[3]));
        m1 = fmin(fmin(s1[0], s1[1]), fmin(s1[2], s1[3]));
        m2 = fmin(fmin(s2[0], s2[1]), fmin(s2[2], s2[3]));
        atomicMin(&lower_bits[b * 3 + 0], (unsigned long long)__double_as_longlong(m0));
        atomicMin(&lower_bits[b * 3 + 1], (unsigned long long)__double_as_longlong(m1));
        atomicMin(&lower_bits[b * 3 + 2], (unsigned long long)__double_as_longlong(m2));
    }

    // --- (b) zero the output grid (write-BW bound; ~87 us at ~6.1 TB/s) ---
    const vfloat4 z4 = {0.f, 0.f, 0.f, 0.f};
    int stride = gridDim.x * blockDim.x;    // 262144
    for (int i = p; i < n4; i += stride)
        __builtin_nontemporal_store(z4, &out4[i]);
}

// ---------------------------------------------------------------------------
// Pass 2: scatter-add upsampled features into the voxel grid.
// idx chain entirely in fp64 (deterministic IEEE == numpy float64 ref).
// ~570K atomics to distinct 64B lines: ~73 MB RMW traffic, ~12-15 us floor.
// ---------------------------------------------------------------------------
__global__ __launch_bounds__(256) void scatter_k(
        const float* __restrict__ nocs, const float* __restrict__ mlog,
        const float* __restrict__ feat, const float* __restrict__ trans,
        const float* __restrict__ scale, const double* __restrict__ lower,
        float* __restrict__ out) {
    int p = blockIdx.x * 256 + threadIdx.x;
    double n0, n1, n2;
    if (!pixel_valid(nocs, mlog, p, n0, n1, n2)) return;

    int b  = p >> 16;
    int hw = p & (HW - 1);
    int h  = hw >> 8;        // / Wn
    int w  = hw & (Wn - 1);

    double sc = (double)scale[b];
    double p0 = (n0 + (double)trans[b * 3 + 0]) * sc - lower[b * 3 + 0];
    double p1 = (n1 + (double)trans[b * 3 + 1]) * sc - lower[b * 3 + 1];
    double p2 = (n2 + (double)trans[b * 3 + 2]) * sc - lower[b * 3 + 2];

    int v0 = (int)floor(p0 * 128.0);
    int v1 = (int)floor(p1 * 128.0);
    int v2 = (int)floor(p2 * 128.0);

    int idx = v0 * (RES * RES) + v1 * RES + v2;
    idx = min(max(idx, 0), R3 - 1);

    // nearest-upsample feature sample: feature[b, c, h/8, w/8]
    const float* fbase = feat + (size_t)b * Cn * FHn * FWn + (h >> 3) * FWn + (w >> 3);
    float* obase = out + (size_t)b * Cn * R3 + idx;
    #pragma unroll
    for (int c = 0; c < Cn; ++c) {
        atomicAdd(obase + (size_t)c * R3, fbase[(size_t)c * FHn * FWn]);
    }
}

extern "C" void kernel_launch(void* const* d_in, const int* in_sizes, int n_in,
                              void* d_out, int out_size, void* d_ws, size_t ws_size,
                              hipStream_t stream) {
    const float* nocs  = (const float*)d_in[0];
    const float* mlog  = (const float*)d_in[1];
    const float* feat  = (const float*)d_in[2];
    const float* trans = (const float*)d_in[3];
    const float* scale = (const float*)d_in[4];
    float* out = (float*)d_out;
    double* lower = (double*)d_ws;         // 12 doubles of scratch

    // 1) init per-batch mins (tiny)
    init_lower_k<<<1, 64, 0, stream>>>(lower);

    // 2) fused: per-batch fp64 min reduce + zero the 512 MiB output grid
    int n4 = out_size / 4;
    fused_reduce_zero_k<<<NPIX / 256, 256, 0, stream>>>(
        nocs, mlog, trans, scale, (unsigned long long*)lower, (vfloat4*)out, n4);

    // 3) scatter-add features into the grid
    scatter_k<<<NPIX / 256, 256, 0, stream>>>(nocs, mlog, feat, trans, scale,
                                              lower, out);
}

// Round 6
// 613.834 us; speedup vs baseline: 1.0646x; 1.0646x over previous
//
#include <hip/hip_runtime.h>
#include <hip/hip_bf16.h>

#define RES 128
#define R3  (RES * RES * RES)   // 2097152

// Problem-fixed shapes (from reference setup_inputs)
constexpr int Bn = 4, Cn = 16, Hn = 256, Wn = 256, FHn = 32, FWn = 32;
constexpr int HW = Hn * Wn;     // 65536
constexpr int NPIX = Bn * HW;   // 262144

// sigmoid(x) > 0.75  <=>  x > ln(3); exact for fp32-grid inputs in fp64
// (disagreement needs |x - ln3| < ~1e-15; fp32 spacing there is ~6e-8).
#define LN3 1.0986122886681098

// ---------------------------------------------------------------------------
// Init per-batch lower mins (fp64) to BIG. Tiny; must precede the atomicMins.
// (Do NOT rely on 0xAA poison bit patterns for min-identity.)
// ---------------------------------------------------------------------------
__global__ void init_lower_k(double* __restrict__ lower) {
    int i = threadIdx.x;
    if (i < Bn * 3) lower[i] = 1e10;
}

// Validity: mask_logit > ln3 AND all 3 nocs channels strictly positive.
__device__ __forceinline__ bool pixel_valid(const float* __restrict__ nocs,
                                            const float* __restrict__ mlog,
                                            int p, double& n0, double& n1, double& n2) {
    if (!((double)mlog[p] > LN3)) return false;
    int b  = p >> 16;        // p / HW
    int hw = p & (HW - 1);
    const float* nb = nocs + (size_t)b * 3 * HW + hw;
    n0 = (double)nb[0];
    n1 = (double)nb[HW];
    n2 = (double)nb[2 * HW];
    return (n0 > 0.0) & (n1 > 0.0) & (n2 > 0.0);
}

__device__ __forceinline__ double wave_min(double v) {
    #pragma unroll
    for (int off = 32; off > 0; off >>= 1)
        v = fmin(v, __shfl_down(v, off, 64));
    return v;
}

// ---------------------------------------------------------------------------
// Fused zero + reduce. Flat shape identical to the best-measured zero kernel:
// 131072 blocks x 256 threads, ONE plain float4 store per thread (no NT hint,
// no grid-stride loop — both regressed in R5). Blocks 0..1023 additionally
// compute the per-batch fp64 min of pc = (nocs+t)*s over valid pixels; the
// branch is block-uniform so __syncthreads inside it is safe. All 1024
// reduce blocks are co-resident in the first dispatch wave, so the reduce
// (~4 us of 5 MiB reads + LDS) hides under the 512 MiB write stream.
// All valid pc >= 0 so unsigned-bit atomicMin preserves float ordering.
// ---------------------------------------------------------------------------
__global__ __launch_bounds__(256) void fused_zero_reduce_k(
        const float* __restrict__ nocs, const float* __restrict__ mlog,
        const float* __restrict__ trans, const float* __restrict__ scale,
        unsigned long long* __restrict__ lower_bits,
        float4* __restrict__ out4, int n4) {
    int tid = threadIdx.x;
    int gid = blockIdx.x * 256 + tid;

    if (blockIdx.x < NPIX / 256) {          // first 1024 blocks: min-reduce
        __shared__ double s0[4], s1[4], s2[4];
        int p = gid;
        int b = p >> 16;                    // whole block shares b

        double m0 = 1e10, m1 = 1e10, m2 = 1e10;
        double n0, n1, n2;
        if (pixel_valid(nocs, mlog, p, n0, n1, n2)) {
            double sc = (double)scale[b];
            m0 = (n0 + (double)trans[b * 3 + 0]) * sc;
            m1 = (n1 + (double)trans[b * 3 + 1]) * sc;
            m2 = (n2 + (double)trans[b * 3 + 2]) * sc;
        }
        m0 = wave_min(m0); m1 = wave_min(m1); m2 = wave_min(m2);
        int wave = tid >> 6;
        if ((tid & 63) == 0) { s0[wave] = m0; s1[wave] = m1; s2[wave] = m2; }
        __syncthreads();
        if (tid == 0) {
            m0 = fmin(fmin(s0[0], s0[1]), fmin(s0[2], s0[3]));
            m1 = fmin(fmin(s1[0], s1[1]), fmin(s1[2], s1[3]));
            m2 = fmin(fmin(s2[0], s2[1]), fmin(s2[2], s2[3]));
            atomicMin(&lower_bits[b * 3 + 0], (unsigned long long)__double_as_longlong(m0));
            atomicMin(&lower_bits[b * 3 + 1], (unsigned long long)__double_as_longlong(m1));
            atomicMin(&lower_bits[b * 3 + 2], (unsigned long long)__double_as_longlong(m2));
        }
    }

    // flat zero store — identical to the 87 us / 6.1 TB/s configuration
    if (gid < n4) out4[gid] = make_float4(0.f, 0.f, 0.f, 0.f);
}

// ---------------------------------------------------------------------------
// Pass 2: scatter-add upsampled features into the voxel grid.
// idx chain entirely in fp64 (deterministic IEEE == numpy float64 ref).
// ~570K atomics to distinct 64B lines: ~51 MB RMW traffic, ~10-15 us floor.
// ---------------------------------------------------------------------------
__global__ __launch_bounds__(256) void scatter_k(
        const float* __restrict__ nocs, const float* __restrict__ mlog,
        const float* __restrict__ feat, const float* __restrict__ trans,
        const float* __restrict__ scale, const double* __restrict__ lower,
        float* __restrict__ out) {
    int p = blockIdx.x * 256 + threadIdx.x;
    double n0, n1, n2;
    if (!pixel_valid(nocs, mlog, p, n0, n1, n2)) return;

    int b  = p >> 16;
    int hw = p & (HW - 1);
    int h  = hw >> 8;        // / Wn
    int w  = hw & (Wn - 1);

    double sc = (double)scale[b];
    double p0 = (n0 + (double)trans[b * 3 + 0]) * sc - lower[b * 3 + 0];
    double p1 = (n1 + (double)trans[b * 3 + 1]) * sc - lower[b * 3 + 1];
    double p2 = (n2 + (double)trans[b * 3 + 2]) * sc - lower[b * 3 + 2];

    int v0 = (int)floor(p0 * 128.0);
    int v1 = (int)floor(p1 * 128.0);
    int v2 = (int)floor(p2 * 128.0);

    int idx = v0 * (RES * RES) + v1 * RES + v2;
    idx = min(max(idx, 0), R3 - 1);

    // nearest-upsample feature sample: feature[b, c, h/8, w/8]
    const float* fbase = feat + (size_t)b * Cn * FHn * FWn + (h >> 3) * FWn + (w >> 3);
    float* obase = out + (size_t)b * Cn * R3 + idx;
    #pragma unroll
    for (int c = 0; c < Cn; ++c) {
        atomicAdd(obase + (size_t)c * R3, fbase[(size_t)c * FHn * FWn]);
    }
}

extern "C" void kernel_launch(void* const* d_in, const int* in_sizes, int n_in,
                              void* d_out, int out_size, void* d_ws, size_t ws_size,
                              hipStream_t stream) {
    const float* nocs  = (const float*)d_in[0];
    const float* mlog  = (const float*)d_in[1];
    const float* feat  = (const float*)d_in[2];
    const float* trans = (const float*)d_in[3];
    const float* scale = (const float*)d_in[4];
    float* out = (float*)d_out;
    double* lower = (double*)d_ws;         // 12 doubles of scratch

    // 1) init per-batch mins (tiny)
    init_lower_k<<<1, 64, 0, stream>>>(lower);

    // 2) fused: zero the 512 MiB grid + per-batch fp64 min reduce
    int n4 = out_size / 4;
    fused_zero_reduce_k<<<(n4 + 255) / 256, 256, 0, stream>>>(
        nocs, mlog, trans, scale, (unsigned long long*)lower, (float4*)out, n4);

    // 3) scatter-add features into the grid
    scatter_k<<<NPIX / 256, 256, 0, stream>>>(nocs, mlog, feat, trans, scale,
                                              lower, out);
}

// Round 8
// 610.864 us; speedup vs baseline: 1.0698x; 1.0049x over previous
//
#include <hip/hip_runtime.h>
#include <hip/hip_bf16.h>

#define RES 128
#define R3  (RES * RES * RES)   // 2097152

// Problem-fixed shapes (from reference setup_inputs)
constexpr int Bn = 4, Cn = 16, Hn = 256, Wn = 256, FHn = 32, FWn = 32;
constexpr int HW = Hn * Wn;     // 65536
constexpr int NPIX = Bn * HW;   // 262144

// sigmoid(x) > 0.75  <=>  x > ln(3); exact for fp32-grid inputs in fp64
// (disagreement needs |x - ln3| < ~1e-15; fp32 spacing there is ~6e-8).
#define LN3 1.0986122886681098

// NOTE (R7 evidence): a single cooperative-launch version of this pipeline
// failed (absmax 12.06) because plain stores to workspace handed across
// cg::grid().sync() are NOT cross-XCD coherent on gfx950 (per-XCD L2;
// Guideline 16). The kernel-boundary structure below gets store->atomic
// visibility for free. The coop win was only ~3% of the timed window.

// ---------------------------------------------------------------------------
// Init per-batch lower mins (fp64) to BIG. Tiny; must precede the atomicMins.
// (Do NOT rely on 0xAA poison bit patterns for min-identity.)
// ---------------------------------------------------------------------------
__global__ void init_lower_k(double* __restrict__ lower) {
    int i = threadIdx.x;
    if (i < Bn * 3) lower[i] = 1e10;
}

// Validity: mask_logit > ln3 AND all 3 nocs channels strictly positive.
__device__ __forceinline__ bool pixel_valid(const float* __restrict__ nocs,
                                            const float* __restrict__ mlog,
                                            int p, double& n0, double& n1, double& n2) {
    if (!((double)mlog[p] > LN3)) return false;
    int b  = p >> 16;        // p / HW
    int hw = p & (HW - 1);
    const float* nb = nocs + (size_t)b * 3 * HW + hw;
    n0 = (double)nb[0];
    n1 = (double)nb[HW];
    n2 = (double)nb[2 * HW];
    return (n0 > 0.0) & (n1 > 0.0) & (n2 > 0.0);
}

__device__ __forceinline__ double wave_min(double v) {
    #pragma unroll
    for (int off = 32; off > 0; off >>= 1)
        v = fmin(v, __shfl_down(v, off, 64));
    return v;
}

// ---------------------------------------------------------------------------
// Fused zero + reduce. Flat shape identical to the best-measured zero kernel:
// 131072 blocks x 256 threads, ONE plain float4 store per thread (no NT hint,
// no grid-stride loop — NT regressed in R5). Blocks 0..1023 additionally
// compute the per-batch fp64 min of pc = (nocs+t)*s over valid pixels; the
// branch is block-uniform so __syncthreads inside it is safe. The reduce
// (~4 us of 5 MiB reads) hides under the 512 MiB write stream.
// All valid pc >= 0 so unsigned-bit atomicMin preserves float ordering.
// ---------------------------------------------------------------------------
__global__ __launch_bounds__(256) void fused_zero_reduce_k(
        const float* __restrict__ nocs, const float* __restrict__ mlog,
        const float* __restrict__ trans, const float* __restrict__ scale,
        unsigned long long* __restrict__ lower_bits,
        float4* __restrict__ out4, int n4) {
    int tid = threadIdx.x;
    int gid = blockIdx.x * 256 + tid;

    if (blockIdx.x < NPIX / 256) {          // first 1024 blocks: min-reduce
        __shared__ double s0[4], s1[4], s2[4];
        int p = gid;
        int b = p >> 16;                    // whole block shares b

        double m0 = 1e10, m1 = 1e10, m2 = 1e10;
        double n0, n1, n2;
        if (pixel_valid(nocs, mlog, p, n0, n1, n2)) {
            double sc = (double)scale[b];
            m0 = (n0 + (double)trans[b * 3 + 0]) * sc;
            m1 = (n1 + (double)trans[b * 3 + 1]) * sc;
            m2 = (n2 + (double)trans[b * 3 + 2]) * sc;
        }
        m0 = wave_min(m0); m1 = wave_min(m1); m2 = wave_min(m2);
        int wave = tid >> 6;
        if ((tid & 63) == 0) { s0[wave] = m0; s1[wave] = m1; s2[wave] = m2; }
        __syncthreads();
        if (tid == 0) {
            m0 = fmin(fmin(s0[0], s0[1]), fmin(s0[2], s0[3]));
            m1 = fmin(fmin(s1[0], s1[1]), fmin(s1[2], s1[3]));
            m2 = fmin(fmin(s2[0], s2[1]), fmin(s2[2], s2[3]));
            atomicMin(&lower_bits[b * 3 + 0], (unsigned long long)__double_as_longlong(m0));
            atomicMin(&lower_bits[b * 3 + 1], (unsigned long long)__double_as_longlong(m1));
            atomicMin(&lower_bits[b * 3 + 2], (unsigned long long)__double_as_longlong(m2));
        }
    }

    // flat zero store — identical to the 87 us / 6.1 TB/s configuration
    if (gid < n4) out4[gid] = make_float4(0.f, 0.f, 0.f, 0.f);
}

// ---------------------------------------------------------------------------
// Pass 2: scatter-add upsampled features into the voxel grid.
// idx chain entirely in fp64 (deterministic IEEE == numpy float64 ref).
// ~570K atomics to distinct 64B lines: ~51 MB RMW traffic, ~10-15 us floor.
// ---------------------------------------------------------------------------
__global__ __launch_bounds__(256) void scatter_k(
        const float* __restrict__ nocs, const float* __restrict__ mlog,
        const float* __restrict__ feat, const float* __restrict__ trans,
        const float* __restrict__ scale, const double* __restrict__ lower,
        float* __restrict__ out) {
    int p = blockIdx.x * 256 + threadIdx.x;
    double n0, n1, n2;
    if (!pixel_valid(nocs, mlog, p, n0, n1, n2)) return;

    int b  = p >> 16;
    int hw = p & (HW - 1);
    int h  = hw >> 8;        // / Wn
    int w  = hw & (Wn - 1);

    double sc = (double)scale[b];
    double p0 = (n0 + (double)trans[b * 3 + 0]) * sc - lower[b * 3 + 0];
    double p1 = (n1 + (double)trans[b * 3 + 1]) * sc - lower[b * 3 + 1];
    double p2 = (n2 + (double)trans[b * 3 + 2]) * sc - lower[b * 3 + 2];

    int v0 = (int)floor(p0 * 128.0);
    int v1 = (int)floor(p1 * 128.0);
    int v2 = (int)floor(p2 * 128.0);

    int idx = v0 * (RES * RES) + v1 * RES + v2;
    idx = min(max(idx, 0), R3 - 1);

    // nearest-upsample feature sample: feature[b, c, h/8, w/8]
    const float* fbase = feat + (size_t)b * Cn * FHn * FWn + (h >> 3) * FWn + (w >> 3);
    float* obase = out + (size_t)b * Cn * R3 + idx;
    #pragma unroll
    for (int c = 0; c < Cn; ++c) {
        atomicAdd(obase + (size_t)c * R3, fbase[(size_t)c * FHn * FWn]);
    }
}

extern "C" void kernel_launch(void* const* d_in, const int* in_sizes, int n_in,
                              void* d_out, int out_size, void* d_ws, size_t ws_size,
                              hipStream_t stream) {
    const float* nocs  = (const float*)d_in[0];
    const float* mlog  = (const float*)d_in[1];
    const float* feat  = (const float*)d_in[2];
    const float* trans = (const float*)d_in[3];
    const float* scale = (const float*)d_in[4];
    float* out = (float*)d_out;
    double* lower = (double*)d_ws;         // 12 doubles of scratch

    // 1) init per-batch mins (tiny)
    init_lower_k<<<1, 64, 0, stream>>>(lower);

    // 2) fused: zero the 512 MiB grid + per-batch fp64 min reduce
    int n4 = out_size / 4;
    fused_zero_reduce_k<<<(n4 + 255) / 256, 256, 0, stream>>>(
        nocs, mlog, trans, scale, (unsigned long long*)lower, (float4*)out, n4);

    // 3) scatter-add features into the grid
    scatter_k<<<NPIX / 256, 256, 0, stream>>>(nocs, mlog, feat, trans, scale,
                                              lower, out);
}